// Round 5
// baseline (239.304 us; speedup 1.0000x reference)
//
#include <hip/hip_runtime.h>

#define F_IN 128
#define HID 16
#define C_OUT 8
#define BSH 6               // bucket = 64 nodes
#define BSZ 64
#define G1 1024             // blocks in count/place passes
#define NBMAX 1600
#define CAP 3072            // max recs staged per bucket (mean 2048, sigma 45 -> 22 sigma)

typedef unsigned int uint;
typedef int   iv4 __attribute__((ext_vector_type(4)));
typedef float fv4 __attribute__((ext_vector_type(4)));

// ---- pass 1: per-(bucket, block) histogram of dst ----
__global__ void count_kernel(const int* __restrict__ dst, uint* __restrict__ counts,
                             int E, int CE, int NB) {
    __shared__ uint h[NBMAX];
    int blk = blockIdx.x, tid = threadIdx.x;
    for (int i = tid; i < NB; i += 256) h[i] = 0;
    __syncthreads();
    int base = blk * CE, end = min(E, base + CE);
    int n = end - base;
    if (n > 0) {
        int n4 = n >> 2;
        const iv4* p = reinterpret_cast<const iv4*>(dst + base);
        for (int i = tid; i < n4; i += 256) {
            iv4 d = __builtin_nontemporal_load(p + i);
            atomicAdd(&h[((uint)d[0]) >> BSH], 1u);
            atomicAdd(&h[((uint)d[1]) >> BSH], 1u);
            atomicAdd(&h[((uint)d[2]) >> BSH], 1u);
            atomicAdd(&h[((uint)d[3]) >> BSH], 1u);
        }
        for (int i = base + (n4 << 2) + tid; i < end; i += 256)
            atomicAdd(&h[((uint)dst[i]) >> BSH], 1u);
    }
    __syncthreads();
    for (int i = tid; i < NB; i += 256)
        counts[(size_t)i * G1 + blk] = h[i];
}

// ---- pass 2a: exclusive scan of each bucket's G1 per-block counts; total -> btot ----
__global__ void scanA_kernel(uint* __restrict__ counts, uint* __restrict__ btot) {
    int b = blockIdx.x, tid = threadIdx.x;
    int lane = tid & 63, wid = tid >> 6;
    uint v = counts[(size_t)b * G1 + tid];
    uint inc = v;
#pragma unroll
    for (int o = 1; o < 64; o <<= 1) {
        uint t = __shfl_up(inc, o);
        if (lane >= o) inc += t;
    }
    __shared__ uint wsum[16];
    if (lane == 63) wsum[wid] = inc;
    __syncthreads();
    if (tid < 16) {
        uint w = wsum[tid], iw = w;
#pragma unroll
        for (int o = 1; o < 16; o <<= 1) {
            uint t = __shfl_up(iw, o);
            if (tid >= o) iw += t;
        }
        wsum[tid] = iw - w;  // exclusive wave base
        if (tid == 15) btot[b] = iw;
    }
    __syncthreads();
    counts[(size_t)b * G1 + tid] = wsum[wid] + inc - v;
}

// ---- pass 2b: exclusive scan of bucket totals -> bbase ----
__global__ void scanB_kernel(const uint* __restrict__ btot, uint* __restrict__ bbase,
                             int NB, int E) {
    __shared__ uint wsum[4];
    __shared__ uint ctot;
    int tid = threadIdx.x, lane = tid & 63, wid = tid >> 6;
    uint base = 0;
    for (int c0 = 0; c0 < NB; c0 += 256) {
        int i = c0 + tid;
        uint v = (i < NB) ? btot[i] : 0u;
        uint inc = v;
#pragma unroll
        for (int o = 1; o < 64; o <<= 1) {
            uint t = __shfl_up(inc, o);
            if (lane >= o) inc += t;
        }
        if (lane == 63) wsum[wid] = inc;
        __syncthreads();
        if (tid == 0) {
            uint s = 0;
#pragma unroll
            for (int k = 0; k < 4; ++k) { uint t = wsum[k]; wsum[k] = s; s += t; }
            ctot = s;
        }
        __syncthreads();
        if (i < NB) bbase[i] = base + wsum[wid] + inc - v;
        base += ctot;
        __syncthreads();
    }
    if (tid == 0) bbase[NB] = (uint)E;
}

// ---- pass 3: place packed records (src | localdst<<17) into bucket segments ----
__global__ void place_kernel(const int* __restrict__ src, const int* __restrict__ dst,
                             const uint* __restrict__ offs, const uint* __restrict__ bbase,
                             uint* __restrict__ rec, int E, int CE, int NB) {
    __shared__ uint cur[NBMAX];
    int blk = blockIdx.x, tid = threadIdx.x;
    for (int i = tid; i < NB; i += 256)
        cur[i] = bbase[i] + offs[(size_t)i * G1 + blk];
    __syncthreads();
    int base = blk * CE, end = min(E, base + CE);
    int n = end - base;
    if (n <= 0) return;
    int n4 = n >> 2;
    const iv4* ps = reinterpret_cast<const iv4*>(src + base);
    const iv4* pd = reinterpret_cast<const iv4*>(dst + base);
    for (int i = tid; i < n4; i += 256) {
        iv4 s = __builtin_nontemporal_load(ps + i);
        iv4 d = __builtin_nontemporal_load(pd + i);
        uint p0 = atomicAdd(&cur[((uint)d[0]) >> BSH], 1u);
        rec[p0] = (uint)s[0] | (((uint)d[0] & (BSZ - 1)) << 17);
        uint p1 = atomicAdd(&cur[((uint)d[1]) >> BSH], 1u);
        rec[p1] = (uint)s[1] | (((uint)d[1] & (BSZ - 1)) << 17);
        uint p2 = atomicAdd(&cur[((uint)d[2]) >> BSH], 1u);
        rec[p2] = (uint)s[2] | (((uint)d[2] & (BSZ - 1)) << 17);
        uint p3 = atomicAdd(&cur[((uint)d[3]) >> BSH], 1u);
        rec[p3] = (uint)s[3] | (((uint)d[3] & (BSZ - 1)) << 17);
    }
    for (int i = base + (n4 << 2) + tid; i < end; i += 256) {
        int d = dst[i];
        uint b = ((uint)d) >> BSH;
        uint p = atomicAdd(&cur[b], 1u);
        rec[p] = (uint)src[i] | (((uint)d & (BSZ - 1)) << 17);
    }
}

// ---- pass 4: within-bucket dst sort (in place), dis, per-node run offsets ----
__global__ void sortdis_kernel(uint* __restrict__ rec, const uint* __restrict__ bbase,
                               uint* __restrict__ nstart, float* __restrict__ dis,
                               int N, int NB) {
    __shared__ uint tmp[CAP];
    __shared__ uint h[BSZ];
    __shared__ uint cur[BSZ];
    int b = blockIdx.x, tid = threadIdx.x;
    if (tid < BSZ) h[tid] = 0;
    uint s0 = bbase[b], s1 = bbase[b + 1];
    uint seg = min(s1 - s0, (uint)CAP);
    __syncthreads();
    for (uint i = tid; i < seg; i += 256) {
        uint r = __builtin_nontemporal_load(rec + s0 + i);
        tmp[i] = r;
        atomicAdd(&h[(r >> 17) & (BSZ - 1)], 1u);
    }
    __syncthreads();
    if (tid < BSZ) {  // single wave
        uint v = h[tid], inc = v;
#pragma unroll
        for (int o = 1; o < BSZ; o <<= 1) {
            uint t = __shfl_up(inc, o);
            if (tid >= o) inc += t;
        }
        uint excl = inc - v;
        cur[tid] = s0 + excl;
        int n = b * BSZ + tid;
        if (n < N) {
            nstart[n] = s0 + excl;
            dis[n] = rsqrtf((float)v + 1.0f);
        }
    }
    if (b == NB - 1 && tid == 0) nstart[N] = s1;
    __syncthreads();
    for (uint i = tid; i < seg; i += 256) {
        uint r = tmp[i];
        uint p = atomicAdd(&cur[(r >> 17) & (BSZ - 1)], 1u);
        rec[p] = r & 0x1FFFFu;   // keep only src
    }
}

// ---- hs1[n,:] = (x[n,:] @ W1) * dis[n] ----
__global__ void h1_kernel(const float* __restrict__ x, const float* __restrict__ W1,
                          const float* __restrict__ dis, float* __restrict__ hs1, int N) {
    __shared__ float w[F_IN * HID];
    for (int t = threadIdx.x; t < F_IN * HID; t += blockDim.x) w[t] = W1[t];
    __syncthreads();
    int row = blockIdx.x * blockDim.x + threadIdx.x;
    if (row >= N) return;
    float acc[HID];
#pragma unroll
    for (int j = 0; j < HID; ++j) acc[j] = 0.f;
    const fv4* xr = reinterpret_cast<const fv4*>(x + (size_t)row * F_IN);
#pragma unroll 4
    for (int k4 = 0; k4 < F_IN / 4; ++k4) {
        fv4 v = __builtin_nontemporal_load(xr + k4);
        int k = k4 * 4;
#pragma unroll
        for (int j = 0; j < HID; ++j) {
            acc[j] += v[0] * w[(k + 0) * HID + j] + v[1] * w[(k + 1) * HID + j]
                    + v[2] * w[(k + 2) * HID + j] + v[3] * w[(k + 3) * HID + j];
        }
    }
    float d = dis[row];
    float4* o = reinterpret_cast<float4*>(hs1 + (size_t)row * HID);
#pragma unroll
    for (int q = 0; q < HID / 4; ++q) {
        float4 r;
        r.x = acc[q * 4 + 0] * d;
        r.y = acc[q * 4 + 1] * d;
        r.z = acc[q * 4 + 2] * d;
        r.w = acc[q * 4 + 3] * d;
        o[q] = r;
    }
}

// ---- layer 1: register segment-sum over sorted runs (8-deep MLP); fused relu + W2 ----
__global__ void agg1_kernel(const uint* __restrict__ rec, const uint* __restrict__ nstart,
                            const float* __restrict__ hs1, const float* __restrict__ dis,
                            const float* __restrict__ b1v, const float* __restrict__ W2,
                            float* __restrict__ hs2, int N) {
    int b = blockIdx.x, tid = threadIdx.x;
    int ld = tid >> 2, q = tid & 3;
    int n = b * BSZ + ld;
    if (n >= N) return;
    uint e = nstart[n], en = nstart[n + 1];
    const float* hq = hs1 + (q << 2);
    float ax = 0.f, ay = 0.f, az = 0.f, aw = 0.f;
    while (e + 8 <= en) {
        uint i0 = __builtin_nontemporal_load(rec + e);
        uint i1 = __builtin_nontemporal_load(rec + e + 1);
        uint i2 = __builtin_nontemporal_load(rec + e + 2);
        uint i3 = __builtin_nontemporal_load(rec + e + 3);
        uint i4 = __builtin_nontemporal_load(rec + e + 4);
        uint i5 = __builtin_nontemporal_load(rec + e + 5);
        uint i6 = __builtin_nontemporal_load(rec + e + 6);
        uint i7 = __builtin_nontemporal_load(rec + e + 7);
        float4 v0 = *reinterpret_cast<const float4*>(hq + ((size_t)i0 << 4));
        float4 v1 = *reinterpret_cast<const float4*>(hq + ((size_t)i1 << 4));
        float4 v2 = *reinterpret_cast<const float4*>(hq + ((size_t)i2 << 4));
        float4 v3 = *reinterpret_cast<const float4*>(hq + ((size_t)i3 << 4));
        float4 v4 = *reinterpret_cast<const float4*>(hq + ((size_t)i4 << 4));
        float4 v5 = *reinterpret_cast<const float4*>(hq + ((size_t)i5 << 4));
        float4 v6 = *reinterpret_cast<const float4*>(hq + ((size_t)i6 << 4));
        float4 v7 = *reinterpret_cast<const float4*>(hq + ((size_t)i7 << 4));
        ax += ((v0.x + v1.x) + (v2.x + v3.x)) + ((v4.x + v5.x) + (v6.x + v7.x));
        ay += ((v0.y + v1.y) + (v2.y + v3.y)) + ((v4.y + v5.y) + (v6.y + v7.y));
        az += ((v0.z + v1.z) + (v2.z + v3.z)) + ((v4.z + v5.z) + (v6.z + v7.z));
        aw += ((v0.w + v1.w) + (v2.w + v3.w)) + ((v4.w + v5.w) + (v6.w + v7.w));
        e += 8;
    }
    if (e + 4 <= en) {
        uint i0 = rec[e], i1 = rec[e + 1], i2 = rec[e + 2], i3 = rec[e + 3];
        float4 v0 = *reinterpret_cast<const float4*>(hq + ((size_t)i0 << 4));
        float4 v1 = *reinterpret_cast<const float4*>(hq + ((size_t)i1 << 4));
        float4 v2 = *reinterpret_cast<const float4*>(hq + ((size_t)i2 << 4));
        float4 v3 = *reinterpret_cast<const float4*>(hq + ((size_t)i3 << 4));
        ax += (v0.x + v1.x) + (v2.x + v3.x);
        ay += (v0.y + v1.y) + (v2.y + v3.y);
        az += (v0.z + v1.z) + (v2.z + v3.z);
        aw += (v0.w + v1.w) + (v2.w + v3.w);
        e += 4;
    }
    while (e < en) {
        uint i0 = rec[e++];
        float4 v = *reinterpret_cast<const float4*>(hq + ((size_t)i0 << 4));
        ax += v.x; ay += v.y; az += v.z; aw += v.w;
    }
    float4 self = *reinterpret_cast<const float4*>(hq + ((size_t)n << 4));
    float dv = dis[n];
    float4 bq = *reinterpret_cast<const float4*>(b1v + (q << 2));
    float r0 = fmaxf(dv * (ax + self.x) + bq.x, 0.f);
    float r1 = fmaxf(dv * (ay + self.y) + bq.y, 0.f);
    float r2 = fmaxf(dv * (az + self.z) + bq.z, 0.f);
    float r3 = fmaxf(dv * (aw + self.w) + bq.w, 0.f);
    float p[C_OUT];
#pragma unroll
    for (int c = 0; c < C_OUT; ++c) {
        p[c] = r0 * W2[(q * 4 + 0) * C_OUT + c] + r1 * W2[(q * 4 + 1) * C_OUT + c]
             + r2 * W2[(q * 4 + 2) * C_OUT + c] + r3 * W2[(q * 4 + 3) * C_OUT + c];
    }
#pragma unroll
    for (int c = 0; c < C_OUT; ++c) p[c] += __shfl_xor(p[c], 1);
#pragma unroll
    for (int c = 0; c < C_OUT; ++c) p[c] += __shfl_xor(p[c], 2);
    float2 o;
    o.x = p[q * 2] * dv;
    o.y = p[q * 2 + 1] * dv;
    *reinterpret_cast<float2*>(hs2 + ((size_t)n << 3) + (q << 1)) = o;
}

// ---- layer 2: 2 lanes/node, float4 gathers, 8-deep MLP; fused fin2 ----
__global__ void agg2_kernel(const uint* __restrict__ rec, const uint* __restrict__ nstart,
                            const float* __restrict__ hs2, const float* __restrict__ dis,
                            const float* __restrict__ b2v, float* __restrict__ out, int N) {
    int tid = threadIdx.x;
    int ld = tid >> 1, q = tid & 1;
    int n = blockIdx.x * 128 + ld;
    if (n >= N) return;
    uint e = nstart[n], en = nstart[n + 1];
    const float* hq = hs2 + (q << 2);
    float ax = 0.f, ay = 0.f, az = 0.f, aw = 0.f;
    while (e + 8 <= en) {
        uint i0 = __builtin_nontemporal_load(rec + e);
        uint i1 = __builtin_nontemporal_load(rec + e + 1);
        uint i2 = __builtin_nontemporal_load(rec + e + 2);
        uint i3 = __builtin_nontemporal_load(rec + e + 3);
        uint i4 = __builtin_nontemporal_load(rec + e + 4);
        uint i5 = __builtin_nontemporal_load(rec + e + 5);
        uint i6 = __builtin_nontemporal_load(rec + e + 6);
        uint i7 = __builtin_nontemporal_load(rec + e + 7);
        float4 v0 = *reinterpret_cast<const float4*>(hq + ((size_t)i0 << 3));
        float4 v1 = *reinterpret_cast<const float4*>(hq + ((size_t)i1 << 3));
        float4 v2 = *reinterpret_cast<const float4*>(hq + ((size_t)i2 << 3));
        float4 v3 = *reinterpret_cast<const float4*>(hq + ((size_t)i3 << 3));
        float4 v4 = *reinterpret_cast<const float4*>(hq + ((size_t)i4 << 3));
        float4 v5 = *reinterpret_cast<const float4*>(hq + ((size_t)i5 << 3));
        float4 v6 = *reinterpret_cast<const float4*>(hq + ((size_t)i6 << 3));
        float4 v7 = *reinterpret_cast<const float4*>(hq + ((size_t)i7 << 3));
        ax += ((v0.x + v1.x) + (v2.x + v3.x)) + ((v4.x + v5.x) + (v6.x + v7.x));
        ay += ((v0.y + v1.y) + (v2.y + v3.y)) + ((v4.y + v5.y) + (v6.y + v7.y));
        az += ((v0.z + v1.z) + (v2.z + v3.z)) + ((v4.z + v5.z) + (v6.z + v7.z));
        aw += ((v0.w + v1.w) + (v2.w + v3.w)) + ((v4.w + v5.w) + (v6.w + v7.w));
        e += 8;
    }
    while (e < en) {
        uint i0 = rec[e++];
        float4 v = *reinterpret_cast<const float4*>(hq + ((size_t)i0 << 3));
        ax += v.x; ay += v.y; az += v.z; aw += v.w;
    }
    float4 self = *reinterpret_cast<const float4*>(hq + ((size_t)n << 3));
    float dv = dis[n];
    float4 o;
    o.x = dv * (ax + self.x) + b2v[q * 4 + 0];
    o.y = dv * (ay + self.y) + b2v[q * 4 + 1];
    o.z = dv * (az + self.z) + b2v[q * 4 + 2];
    o.w = dv * (aw + self.w) + b2v[q * 4 + 3];
    *reinterpret_cast<float4*>(out + ((size_t)n << 3) + (q << 2)) = o;
}

extern "C" void kernel_launch(void* const* d_in, const int* in_sizes, int n_in,
                              void* d_out, int out_size, void* d_ws, size_t ws_size,
                              hipStream_t stream) {
    const float* x  = (const float*)d_in[0];
    const int*   ei = (const int*)d_in[1];
    const float* W1 = (const float*)d_in[2];
    const float* b1 = (const float*)d_in[3];
    const float* W2 = (const float*)d_in[4];
    const float* b2 = (const float*)d_in[5];
    float* out = (float*)d_out;

    int N = in_sizes[0] / F_IN;
    int E = in_sizes[1] / 2;
    const int* src = ei;
    const int* dst = ei + E;

    int NB = (N + BSZ - 1) / BSZ;                    // 1563
    int CE = (((E + G1 - 1) / G1) + 3) & ~3;         // per-block chunk, multiple of 4

    // workspace layout (4-byte units)
    uint* counts = (uint*)d_ws;                      // NB*G1
    uint* btot   = counts + (size_t)NB * G1;         // NB
    uint* bbase  = btot + NB;                        // NB+1
    uint* rec    = bbase + NB + 1;                   // E
    uint* nstart = rec + E;                          // N+1
    float* dis   = (float*)(nstart + N + 1);         // N
    float* hs1   = dis + N;                          // 16N
    float* hs2   = hs1 + (size_t)16 * N;             // 8N

    const int B = 256;
    count_kernel<<<G1, B, 0, stream>>>(dst, counts, E, CE, NB);
    scanA_kernel<<<NB, G1, 0, stream>>>(counts, btot);
    scanB_kernel<<<1, B, 0, stream>>>(btot, bbase, NB, E);
    place_kernel<<<G1, B, 0, stream>>>(src, dst, counts, bbase, rec, E, CE, NB);
    sortdis_kernel<<<NB, B, 0, stream>>>(rec, bbase, nstart, dis, N, NB);
    h1_kernel<<<(N + B - 1) / B, B, 0, stream>>>(x, W1, dis, hs1, N);
    agg1_kernel<<<NB, B, 0, stream>>>(rec, nstart, hs1, dis, b1, W2, hs2, N);
    agg2_kernel<<<(N + 127) / 128, B, 0, stream>>>(rec, nstart, hs2, dis, b2, out, N);
}

// Round 6
// 189.479 us; speedup vs baseline: 1.2630x; 1.2630x over previous
//
#include <hip/hip_runtime.h>
#include <hip/hip_fp16.h>

#define F_IN 128
#define HID 16
#define C_OUT 8
#define BSH 6               // bucket = 64 nodes
#define BSZ 64
#define G1 1024             // blocks in count/place passes
#define NBMAX 1600
#define CAP 3072            // max recs staged per bucket (mean 2048, sigma 45 -> 22 sigma)

typedef unsigned int uint;

// ---- pass 1: per-(bucket, block) histogram of dst ----
__global__ void count_kernel(const int* __restrict__ dst, uint* __restrict__ counts,
                             int E, int CE, int NB) {
    __shared__ uint h[NBMAX];
    int blk = blockIdx.x, tid = threadIdx.x;
    for (int i = tid; i < NB; i += 256) h[i] = 0;
    __syncthreads();
    int base = blk * CE, end = min(E, base + CE);
    int n = end - base;
    if (n > 0) {
        int n4 = n >> 2;
        const int4* p = reinterpret_cast<const int4*>(dst + base);
        for (int i = tid; i < n4; i += 256) {
            int4 d = p[i];
            atomicAdd(&h[((uint)d.x) >> BSH], 1u);
            atomicAdd(&h[((uint)d.y) >> BSH], 1u);
            atomicAdd(&h[((uint)d.z) >> BSH], 1u);
            atomicAdd(&h[((uint)d.w) >> BSH], 1u);
        }
        for (int i = base + (n4 << 2) + tid; i < end; i += 256)
            atomicAdd(&h[((uint)dst[i]) >> BSH], 1u);
    }
    __syncthreads();
    for (int i = tid; i < NB; i += 256)
        counts[(size_t)i * G1 + blk] = h[i];
}

// ---- pass 2a: exclusive scan of each bucket's G1 per-block counts; total -> btot ----
__global__ void scanA_kernel(uint* __restrict__ counts, uint* __restrict__ btot) {
    int b = blockIdx.x, tid = threadIdx.x;
    int lane = tid & 63, wid = tid >> 6;
    uint v = counts[(size_t)b * G1 + tid];
    uint inc = v;
#pragma unroll
    for (int o = 1; o < 64; o <<= 1) {
        uint t = __shfl_up(inc, o);
        if (lane >= o) inc += t;
    }
    __shared__ uint wsum[16];
    if (lane == 63) wsum[wid] = inc;
    __syncthreads();
    if (tid < 16) {
        uint w = wsum[tid], iw = w;
#pragma unroll
        for (int o = 1; o < 16; o <<= 1) {
            uint t = __shfl_up(iw, o);
            if (tid >= o) iw += t;
        }
        wsum[tid] = iw - w;  // exclusive wave base
        if (tid == 15) btot[b] = iw;
    }
    __syncthreads();
    counts[(size_t)b * G1 + tid] = wsum[wid] + inc - v;
}

// ---- pass 2b: exclusive scan of bucket totals -> bbase ----
__global__ void scanB_kernel(const uint* __restrict__ btot, uint* __restrict__ bbase,
                             int NB, int E) {
    __shared__ uint wsum[4];
    __shared__ uint ctot;
    int tid = threadIdx.x, lane = tid & 63, wid = tid >> 6;
    uint base = 0;
    for (int c0 = 0; c0 < NB; c0 += 256) {
        int i = c0 + tid;
        uint v = (i < NB) ? btot[i] : 0u;
        uint inc = v;
#pragma unroll
        for (int o = 1; o < 64; o <<= 1) {
            uint t = __shfl_up(inc, o);
            if (lane >= o) inc += t;
        }
        if (lane == 63) wsum[wid] = inc;
        __syncthreads();
        if (tid == 0) {
            uint s = 0;
#pragma unroll
            for (int k = 0; k < 4; ++k) { uint t = wsum[k]; wsum[k] = s; s += t; }
            ctot = s;
        }
        __syncthreads();
        if (i < NB) bbase[i] = base + wsum[wid] + inc - v;
        base += ctot;
        __syncthreads();
    }
    if (tid == 0) bbase[NB] = (uint)E;
}

// ---- pass 3: place packed records (src | localdst<<17) into bucket segments ----
__global__ void place_kernel(const int* __restrict__ src, const int* __restrict__ dst,
                             const uint* __restrict__ offs, const uint* __restrict__ bbase,
                             uint* __restrict__ rec, int E, int CE, int NB) {
    __shared__ uint cur[NBMAX];
    int blk = blockIdx.x, tid = threadIdx.x;
    for (int i = tid; i < NB; i += 256)
        cur[i] = bbase[i] + offs[(size_t)i * G1 + blk];
    __syncthreads();
    int base = blk * CE, end = min(E, base + CE);
    int n = end - base;
    if (n <= 0) return;
    int n4 = n >> 2;
    const int4* ps = reinterpret_cast<const int4*>(src + base);
    const int4* pd = reinterpret_cast<const int4*>(dst + base);
    for (int i = tid; i < n4; i += 256) {
        int4 s = ps[i];
        int4 d = pd[i];
        uint p0 = atomicAdd(&cur[((uint)d.x) >> BSH], 1u);
        rec[p0] = (uint)s.x | (((uint)d.x & (BSZ - 1)) << 17);
        uint p1 = atomicAdd(&cur[((uint)d.y) >> BSH], 1u);
        rec[p1] = (uint)s.y | (((uint)d.y & (BSZ - 1)) << 17);
        uint p2 = atomicAdd(&cur[((uint)d.z) >> BSH], 1u);
        rec[p2] = (uint)s.z | (((uint)d.z & (BSZ - 1)) << 17);
        uint p3 = atomicAdd(&cur[((uint)d.w) >> BSH], 1u);
        rec[p3] = (uint)s.w | (((uint)d.w & (BSZ - 1)) << 17);
    }
    for (int i = base + (n4 << 2) + tid; i < end; i += 256) {
        int d = dst[i];
        uint b = ((uint)d) >> BSH;
        uint p = atomicAdd(&cur[b], 1u);
        rec[p] = (uint)src[i] | (((uint)d & (BSZ - 1)) << 17);
    }
}

// ---- pass 4: within-bucket dst sort (in place), dis, per-node run offsets ----
__global__ void sortdis_kernel(uint* __restrict__ rec, const uint* __restrict__ bbase,
                               uint* __restrict__ nstart, float* __restrict__ dis,
                               int N, int NB) {
    __shared__ uint tmp[CAP];
    __shared__ uint h[BSZ];
    __shared__ uint cur[BSZ];
    int b = blockIdx.x, tid = threadIdx.x;
    if (tid < BSZ) h[tid] = 0;
    uint s0 = bbase[b], s1 = bbase[b + 1];
    uint seg = min(s1 - s0, (uint)CAP);
    __syncthreads();
    for (uint i = tid; i < seg; i += 256) {
        uint r = rec[s0 + i];
        tmp[i] = r;
        atomicAdd(&h[(r >> 17) & (BSZ - 1)], 1u);
    }
    __syncthreads();
    if (tid < BSZ) {  // single wave
        uint v = h[tid], inc = v;
#pragma unroll
        for (int o = 1; o < BSZ; o <<= 1) {
            uint t = __shfl_up(inc, o);
            if (tid >= o) inc += t;
        }
        uint excl = inc - v;
        cur[tid] = s0 + excl;
        int n = b * BSZ + tid;
        if (n < N) {
            nstart[n] = s0 + excl;
            dis[n] = rsqrtf((float)v + 1.0f);
        }
    }
    if (b == NB - 1 && tid == 0) nstart[N] = s1;
    __syncthreads();
    for (uint i = tid; i < seg; i += 256) {
        uint r = tmp[i];
        uint p = atomicAdd(&cur[(r >> 17) & (BSZ - 1)], 1u);
        rec[p] = r & 0x1FFFFu;   // keep only src
    }
}

// ---- hs1[n,:] = fp16((x[n,:] @ W1) * dis[n])  -- 3.2 MB table, fits per-XCD L2 ----
__global__ void h1_kernel(const float* __restrict__ x, const float* __restrict__ W1,
                          const float* __restrict__ dis, __half* __restrict__ hs1, int N) {
    __shared__ float w[F_IN * HID];
    for (int t = threadIdx.x; t < F_IN * HID; t += blockDim.x) w[t] = W1[t];
    __syncthreads();
    int row = blockIdx.x * blockDim.x + threadIdx.x;
    if (row >= N) return;
    float acc[HID];
#pragma unroll
    for (int j = 0; j < HID; ++j) acc[j] = 0.f;
    const float4* xr = reinterpret_cast<const float4*>(x + (size_t)row * F_IN);
#pragma unroll 4
    for (int k4 = 0; k4 < F_IN / 4; ++k4) {
        float4 v = xr[k4];
        int k = k4 * 4;
#pragma unroll
        for (int j = 0; j < HID; ++j) {
            acc[j] += v.x * w[(k + 0) * HID + j] + v.y * w[(k + 1) * HID + j]
                    + v.z * w[(k + 2) * HID + j] + v.w * w[(k + 3) * HID + j];
        }
    }
    float d = dis[row];
    uint u[8];
#pragma unroll
    for (int p = 0; p < 8; ++p) {
        __half2 hh = __floats2half2_rn(acc[2 * p] * d, acc[2 * p + 1] * d);
        u[p] = *reinterpret_cast<uint*>(&hh);
    }
    uint4* o = reinterpret_cast<uint4*>(hs1 + ((size_t)row << 4));
    o[0] = make_uint4(u[0], u[1], u[2], u[3]);
    o[1] = make_uint4(u[4], u[5], u[6], u[7]);
}

__device__ inline void acc8(uint4 v, float* a) {
    float2 f;
    f = __half22float2(*reinterpret_cast<const __half2*>(&v.x)); a[0] += f.x; a[1] += f.y;
    f = __half22float2(*reinterpret_cast<const __half2*>(&v.y)); a[2] += f.x; a[3] += f.y;
    f = __half22float2(*reinterpret_cast<const __half2*>(&v.z)); a[4] += f.x; a[5] += f.y;
    f = __half22float2(*reinterpret_cast<const __half2*>(&v.w)); a[6] += f.x; a[7] += f.y;
}

// ---- layer 1: 2 lanes/node, 16B fp16 gathers (L2-resident table), 8-deep MLP;
//      fused relu + W2 with one xor-shuffle ----
__global__ void agg1_kernel(const uint* __restrict__ rec, const uint* __restrict__ nstart,
                            const __half* __restrict__ hs1, const float* __restrict__ dis,
                            const float* __restrict__ b1v, const float* __restrict__ W2,
                            float* __restrict__ hs2, int N) {
    __shared__ float w2s[HID * C_OUT];
    __shared__ float b1s[HID];
    int tid = threadIdx.x;
    if (tid < HID * C_OUT) w2s[tid] = W2[tid];
    if (tid < HID) b1s[tid] = b1v[tid];
    __syncthreads();
    int ldn = tid >> 1, q = tid & 1;
    int n = blockIdx.x * 128 + ldn;
    if (n >= N) return;
    uint e = nstart[n], en = nstart[n + 1];
    const uint4* hb = reinterpret_cast<const uint4*>(hs1) + q;  // row = idx*2 + q
    float a[8];
#pragma unroll
    for (int j = 0; j < 8; ++j) a[j] = 0.f;
    while (e + 8 <= en) {
        uint i0 = __builtin_nontemporal_load(rec + e);
        uint i1 = __builtin_nontemporal_load(rec + e + 1);
        uint i2 = __builtin_nontemporal_load(rec + e + 2);
        uint i3 = __builtin_nontemporal_load(rec + e + 3);
        uint i4 = __builtin_nontemporal_load(rec + e + 4);
        uint i5 = __builtin_nontemporal_load(rec + e + 5);
        uint i6 = __builtin_nontemporal_load(rec + e + 6);
        uint i7 = __builtin_nontemporal_load(rec + e + 7);
        uint4 v0 = hb[(size_t)i0 << 1];
        uint4 v1 = hb[(size_t)i1 << 1];
        uint4 v2 = hb[(size_t)i2 << 1];
        uint4 v3 = hb[(size_t)i3 << 1];
        uint4 v4 = hb[(size_t)i4 << 1];
        uint4 v5 = hb[(size_t)i5 << 1];
        uint4 v6 = hb[(size_t)i6 << 1];
        uint4 v7 = hb[(size_t)i7 << 1];
        acc8(v0, a); acc8(v1, a); acc8(v2, a); acc8(v3, a);
        acc8(v4, a); acc8(v5, a); acc8(v6, a); acc8(v7, a);
        e += 8;
    }
    while (e < en) {
        uint i0 = __builtin_nontemporal_load(rec + e);
        uint4 v = hb[(size_t)i0 << 1];
        acc8(v, a);
        ++e;
    }
    uint4 sv = hb[(size_t)n << 1];
    float s[8];
    {
        float2 f;
        f = __half22float2(*reinterpret_cast<const __half2*>(&sv.x)); s[0] = f.x; s[1] = f.y;
        f = __half22float2(*reinterpret_cast<const __half2*>(&sv.y)); s[2] = f.x; s[3] = f.y;
        f = __half22float2(*reinterpret_cast<const __half2*>(&sv.z)); s[4] = f.x; s[5] = f.y;
        f = __half22float2(*reinterpret_cast<const __half2*>(&sv.w)); s[6] = f.x; s[7] = f.y;
    }
    float dv = dis[n];
    float r[8];
#pragma unroll
    for (int j = 0; j < 8; ++j)
        r[j] = fmaxf(dv * (a[j] + s[j]) + b1s[q * 8 + j], 0.f);
    float p[C_OUT];
#pragma unroll
    for (int c = 0; c < C_OUT; ++c) {
        float t = 0.f;
#pragma unroll
        for (int j = 0; j < 8; ++j) t += r[j] * w2s[(q * 8 + j) * C_OUT + c];
        p[c] = t;
    }
#pragma unroll
    for (int c = 0; c < C_OUT; ++c) p[c] += __shfl_xor(p[c], 1);
    float4 o;
    o.x = p[q * 4 + 0] * dv;
    o.y = p[q * 4 + 1] * dv;
    o.z = p[q * 4 + 2] * dv;
    o.w = p[q * 4 + 3] * dv;
    *reinterpret_cast<float4*>(hs2 + ((size_t)n << 3) + (q << 2)) = o;
}

// ---- layer 2: 2 lanes/node, float4 gathers (3.2 MB fp32 table), 8-deep MLP; fused fin2 ----
__global__ void agg2_kernel(const uint* __restrict__ rec, const uint* __restrict__ nstart,
                            const float* __restrict__ hs2, const float* __restrict__ dis,
                            const float* __restrict__ b2v, float* __restrict__ out, int N) {
    int tid = threadIdx.x;
    int ldn = tid >> 1, q = tid & 1;
    int n = blockIdx.x * 128 + ldn;
    if (n >= N) return;
    uint e = nstart[n], en = nstart[n + 1];
    const float* hq = hs2 + (q << 2);
    float ax = 0.f, ay = 0.f, az = 0.f, aw = 0.f;
    while (e + 8 <= en) {
        uint i0 = __builtin_nontemporal_load(rec + e);
        uint i1 = __builtin_nontemporal_load(rec + e + 1);
        uint i2 = __builtin_nontemporal_load(rec + e + 2);
        uint i3 = __builtin_nontemporal_load(rec + e + 3);
        uint i4 = __builtin_nontemporal_load(rec + e + 4);
        uint i5 = __builtin_nontemporal_load(rec + e + 5);
        uint i6 = __builtin_nontemporal_load(rec + e + 6);
        uint i7 = __builtin_nontemporal_load(rec + e + 7);
        float4 v0 = *reinterpret_cast<const float4*>(hq + ((size_t)i0 << 3));
        float4 v1 = *reinterpret_cast<const float4*>(hq + ((size_t)i1 << 3));
        float4 v2 = *reinterpret_cast<const float4*>(hq + ((size_t)i2 << 3));
        float4 v3 = *reinterpret_cast<const float4*>(hq + ((size_t)i3 << 3));
        float4 v4 = *reinterpret_cast<const float4*>(hq + ((size_t)i4 << 3));
        float4 v5 = *reinterpret_cast<const float4*>(hq + ((size_t)i5 << 3));
        float4 v6 = *reinterpret_cast<const float4*>(hq + ((size_t)i6 << 3));
        float4 v7 = *reinterpret_cast<const float4*>(hq + ((size_t)i7 << 3));
        ax += ((v0.x + v1.x) + (v2.x + v3.x)) + ((v4.x + v5.x) + (v6.x + v7.x));
        ay += ((v0.y + v1.y) + (v2.y + v3.y)) + ((v4.y + v5.y) + (v6.y + v7.y));
        az += ((v0.z + v1.z) + (v2.z + v3.z)) + ((v4.z + v5.z) + (v6.z + v7.z));
        aw += ((v0.w + v1.w) + (v2.w + v3.w)) + ((v4.w + v5.w) + (v6.w + v7.w));
        e += 8;
    }
    while (e < en) {
        uint i0 = __builtin_nontemporal_load(rec + e);
        float4 v = *reinterpret_cast<const float4*>(hq + ((size_t)i0 << 3));
        ax += v.x; ay += v.y; az += v.z; aw += v.w;
        ++e;
    }
    float4 self = *reinterpret_cast<const float4*>(hq + ((size_t)n << 3));
    float dv = dis[n];
    float4 o;
    o.x = dv * (ax + self.x) + b2v[q * 4 + 0];
    o.y = dv * (ay + self.y) + b2v[q * 4 + 1];
    o.z = dv * (az + self.z) + b2v[q * 4 + 2];
    o.w = dv * (aw + self.w) + b2v[q * 4 + 3];
    *reinterpret_cast<float4*>(out + ((size_t)n << 3) + (q << 2)) = o;
}

extern "C" void kernel_launch(void* const* d_in, const int* in_sizes, int n_in,
                              void* d_out, int out_size, void* d_ws, size_t ws_size,
                              hipStream_t stream) {
    const float* x  = (const float*)d_in[0];
    const int*   ei = (const int*)d_in[1];
    const float* W1 = (const float*)d_in[2];
    const float* b1 = (const float*)d_in[3];
    const float* W2 = (const float*)d_in[4];
    const float* b2 = (const float*)d_in[5];
    float* out = (float*)d_out;

    int N = in_sizes[0] / F_IN;
    int E = in_sizes[1] / 2;
    const int* src = ei;
    const int* dst = ei + E;

    int NB = (N + BSZ - 1) / BSZ;                    // 1563
    int CE = (((E + G1 - 1) / G1) + 3) & ~3;         // per-block chunk, multiple of 4

    // workspace layout (4-byte units); 16B-sensitive arrays first
    float*  hs2   = (float*)d_ws;                    // 8N floats   (16B aligned)
    __half* hs1   = (__half*)(hs2 + (size_t)8 * N);  // 16N halves = 8N words (16B aligned)
    float*  dis   = (float*)(hs2 + (size_t)16 * N);  // N
    uint*   nstart = (uint*)(dis + N);               // N+1
    uint*   rec   = nstart + N + 1;                  // E
    uint*   counts = rec + E;                        // NB*G1
    uint*   btot  = counts + (size_t)NB * G1;        // NB
    uint*   bbase = btot + NB;                       // NB+1

    const int B = 256;
    count_kernel<<<G1, B, 0, stream>>>(dst, counts, E, CE, NB);
    scanA_kernel<<<NB, G1, 0, stream>>>(counts, btot);
    scanB_kernel<<<1, B, 0, stream>>>(btot, bbase, NB, E);
    place_kernel<<<G1, B, 0, stream>>>(src, dst, counts, bbase, rec, E, CE, NB);
    sortdis_kernel<<<NB, B, 0, stream>>>(rec, bbase, nstart, dis, N, NB);
    h1_kernel<<<(N + B - 1) / B, B, 0, stream>>>(x, W1, dis, hs1, N);
    agg1_kernel<<<(N + 127) / 128, B, 0, stream>>>(rec, nstart, hs1, dis, b1, W2, hs2, N);
    agg2_kernel<<<(N + 127) / 128, B, 0, stream>>>(rec, nstart, hs2, dis, b2, out, N);
}

// Round 7
// 160.316 us; speedup vs baseline: 1.4927x; 1.1819x over previous
//
#include <hip/hip_runtime.h>
#include <hip/hip_fp16.h>

#define F_IN 128
#define HID 16
#define C_OUT 8
#define BSH 6               // bucket = 64 nodes
#define BSZ 64
#define G1 1024             // blocks in count/place passes
#define NBMAX 1600
#define CAP 3072            // max recs staged per bucket (mean 2048, sigma 45 -> 22 sigma)

typedef unsigned int uint;

// XCD-adjacency chunk swizzle: blocks on the same XCD (blk%8 under round-robin
// dispatch) own ADJACENT chunks, so each 64B line of rec (written by ~8 adjacent
// chunks' private ranges) is assembled within ONE XCD's L2 -> single writeback.
__device__ inline int chunk_of_block(int blk) {
    return ((blk & 7) << 7) | (blk >> 3);   // G1 = 1024 = 8 * 128
}

// ---- pass 1: per-(bucket, chunk) histogram of dst ----
__global__ void count_kernel(const int* __restrict__ dst, uint* __restrict__ counts,
                             int E, int CE, int NB) {
    __shared__ uint h[NBMAX];
    int chunk = chunk_of_block(blockIdx.x), tid = threadIdx.x;
    for (int i = tid; i < NB; i += 256) h[i] = 0;
    __syncthreads();
    int base = chunk * CE, end = min(E, base + CE);
    int n = end - base;
    if (n > 0) {
        int n4 = n >> 2;
        const int4* p = reinterpret_cast<const int4*>(dst + base);
        for (int i = tid; i < n4; i += 256) {
            int4 d = p[i];
            atomicAdd(&h[((uint)d.x) >> BSH], 1u);
            atomicAdd(&h[((uint)d.y) >> BSH], 1u);
            atomicAdd(&h[((uint)d.z) >> BSH], 1u);
            atomicAdd(&h[((uint)d.w) >> BSH], 1u);
        }
        for (int i = base + (n4 << 2) + tid; i < end; i += 256)
            atomicAdd(&h[((uint)dst[i]) >> BSH], 1u);
    }
    __syncthreads();
    for (int i = tid; i < NB; i += 256)
        counts[(size_t)i * G1 + chunk] = h[i];
}

// ---- pass 2a: exclusive scan of each bucket's G1 per-chunk counts; total -> btot ----
__global__ void scanA_kernel(uint* __restrict__ counts, uint* __restrict__ btot) {
    int b = blockIdx.x, tid = threadIdx.x;
    int lane = tid & 63, wid = tid >> 6;
    uint v = counts[(size_t)b * G1 + tid];
    uint inc = v;
#pragma unroll
    for (int o = 1; o < 64; o <<= 1) {
        uint t = __shfl_up(inc, o);
        if (lane >= o) inc += t;
    }
    __shared__ uint wsum[16];
    if (lane == 63) wsum[wid] = inc;
    __syncthreads();
    if (tid < 16) {
        uint w = wsum[tid], iw = w;
#pragma unroll
        for (int o = 1; o < 16; o <<= 1) {
            uint t = __shfl_up(iw, o);
            if (tid >= o) iw += t;
        }
        wsum[tid] = iw - w;  // exclusive wave base
        if (tid == 15) btot[b] = iw;
    }
    __syncthreads();
    counts[(size_t)b * G1 + tid] = wsum[wid] + inc - v;
}

// ---- pass 2b: exclusive scan of bucket totals -> bbase ----
__global__ void scanB_kernel(const uint* __restrict__ btot, uint* __restrict__ bbase,
                             int NB, int E) {
    __shared__ uint wsum[4];
    __shared__ uint ctot;
    int tid = threadIdx.x, lane = tid & 63, wid = tid >> 6;
    uint base = 0;
    for (int c0 = 0; c0 < NB; c0 += 256) {
        int i = c0 + tid;
        uint v = (i < NB) ? btot[i] : 0u;
        uint inc = v;
#pragma unroll
        for (int o = 1; o < 64; o <<= 1) {
            uint t = __shfl_up(inc, o);
            if (lane >= o) inc += t;
        }
        if (lane == 63) wsum[wid] = inc;
        __syncthreads();
        if (tid == 0) {
            uint s = 0;
#pragma unroll
            for (int k = 0; k < 4; ++k) { uint t = wsum[k]; wsum[k] = s; s += t; }
            ctot = s;
        }
        __syncthreads();
        if (i < NB) bbase[i] = base + wsum[wid] + inc - v;
        base += ctot;
        __syncthreads();
    }
    if (tid == 0) bbase[NB] = (uint)E;
}

// ---- pass 3: place packed records (src | localdst<<17) into bucket segments ----
__global__ void place_kernel(const int* __restrict__ src, const int* __restrict__ dst,
                             const uint* __restrict__ offs, const uint* __restrict__ bbase,
                             uint* __restrict__ rec, int E, int CE, int NB) {
    __shared__ uint cur[NBMAX];
    int chunk = chunk_of_block(blockIdx.x), tid = threadIdx.x;
    for (int i = tid; i < NB; i += 256)
        cur[i] = bbase[i] + offs[(size_t)i * G1 + chunk];
    __syncthreads();
    int base = chunk * CE, end = min(E, base + CE);
    int n = end - base;
    if (n <= 0) return;
    int n4 = n >> 2;
    const int4* ps = reinterpret_cast<const int4*>(src + base);
    const int4* pd = reinterpret_cast<const int4*>(dst + base);
    for (int i = tid; i < n4; i += 256) {
        int4 s = ps[i];
        int4 d = pd[i];
        uint p0 = atomicAdd(&cur[((uint)d.x) >> BSH], 1u);
        rec[p0] = (uint)s.x | (((uint)d.x & (BSZ - 1)) << 17);
        uint p1 = atomicAdd(&cur[((uint)d.y) >> BSH], 1u);
        rec[p1] = (uint)s.y | (((uint)d.y & (BSZ - 1)) << 17);
        uint p2 = atomicAdd(&cur[((uint)d.z) >> BSH], 1u);
        rec[p2] = (uint)s.z | (((uint)d.z & (BSZ - 1)) << 17);
        uint p3 = atomicAdd(&cur[((uint)d.w) >> BSH], 1u);
        rec[p3] = (uint)s.w | (((uint)d.w & (BSZ - 1)) << 17);
    }
    for (int i = base + (n4 << 2) + tid; i < end; i += 256) {
        int d = dst[i];
        uint b = ((uint)d) >> BSH;
        uint p = atomicAdd(&cur[b], 1u);
        rec[p] = (uint)src[i] | (((uint)d & (BSZ - 1)) << 17);
    }
}

// ---- pass 4: within-bucket dst sort (in place), dis, per-node run offsets ----
__global__ void sortdis_kernel(uint* __restrict__ rec, const uint* __restrict__ bbase,
                               uint* __restrict__ nstart, float* __restrict__ dis,
                               int N, int NB) {
    __shared__ uint tmp[CAP];
    __shared__ uint h[BSZ];
    __shared__ uint cur[BSZ];
    int b = blockIdx.x, tid = threadIdx.x;
    if (tid < BSZ) h[tid] = 0;
    uint s0 = bbase[b], s1 = bbase[b + 1];
    uint seg = min(s1 - s0, (uint)CAP);
    __syncthreads();
    for (uint i = tid; i < seg; i += 256) {
        uint r = rec[s0 + i];
        tmp[i] = r;
        atomicAdd(&h[(r >> 17) & (BSZ - 1)], 1u);
    }
    __syncthreads();
    if (tid < BSZ) {  // single wave
        uint v = h[tid], inc = v;
#pragma unroll
        for (int o = 1; o < BSZ; o <<= 1) {
            uint t = __shfl_up(inc, o);
            if (tid >= o) inc += t;
        }
        uint excl = inc - v;
        cur[tid] = s0 + excl;
        int n = b * BSZ + tid;
        if (n < N) {
            nstart[n] = s0 + excl;
            dis[n] = rsqrtf((float)v + 1.0f);
        }
    }
    if (b == NB - 1 && tid == 0) nstart[N] = s1;
    __syncthreads();
    for (uint i = tid; i < seg; i += 256) {
        uint r = tmp[i];
        uint p = atomicAdd(&cur[(r >> 17) & (BSZ - 1)], 1u);
        rec[p] = r & 0x1FFFFu;   // keep only src
    }
}

// ---- hs1[n,:] = fp16((x[n,:] @ W1) * dis[n])  -- 3.2 MB table, fits per-XCD L2 ----
__global__ void h1_kernel(const float* __restrict__ x, const float* __restrict__ W1,
                          const float* __restrict__ dis, __half* __restrict__ hs1, int N) {
    __shared__ float w[F_IN * HID];
    for (int t = threadIdx.x; t < F_IN * HID; t += blockDim.x) w[t] = W1[t];
    __syncthreads();
    int row = blockIdx.x * blockDim.x + threadIdx.x;
    if (row >= N) return;
    float acc[HID];
#pragma unroll
    for (int j = 0; j < HID; ++j) acc[j] = 0.f;
    const float4* xr = reinterpret_cast<const float4*>(x + (size_t)row * F_IN);
#pragma unroll 4
    for (int k4 = 0; k4 < F_IN / 4; ++k4) {
        float4 v = xr[k4];
        int k = k4 * 4;
#pragma unroll
        for (int j = 0; j < HID; ++j) {
            acc[j] += v.x * w[(k + 0) * HID + j] + v.y * w[(k + 1) * HID + j]
                    + v.z * w[(k + 2) * HID + j] + v.w * w[(k + 3) * HID + j];
        }
    }
    float d = dis[row];
    uint u[8];
#pragma unroll
    for (int p = 0; p < 8; ++p) {
        __half2 hh = __floats2half2_rn(acc[2 * p] * d, acc[2 * p + 1] * d);
        u[p] = *reinterpret_cast<uint*>(&hh);
    }
    uint4* o = reinterpret_cast<uint4*>(hs1 + ((size_t)row << 4));
    o[0] = make_uint4(u[0], u[1], u[2], u[3]);
    o[1] = make_uint4(u[4], u[5], u[6], u[7]);
}

__device__ inline void acc8(uint4 v, float* a) {
    float2 f;
    f = __half22float2(*reinterpret_cast<const __half2*>(&v.x)); a[0] += f.x; a[1] += f.y;
    f = __half22float2(*reinterpret_cast<const __half2*>(&v.y)); a[2] += f.x; a[3] += f.y;
    f = __half22float2(*reinterpret_cast<const __half2*>(&v.z)); a[4] += f.x; a[5] += f.y;
    f = __half22float2(*reinterpret_cast<const __half2*>(&v.w)); a[6] += f.x; a[7] += f.y;
}

// ---- layer 1: 2 lanes/node, 16B fp16 gathers (L2-resident table), 8-deep MLP;
//      fused relu + W2 with one xor-shuffle ----
__global__ void agg1_kernel(const uint* __restrict__ rec, const uint* __restrict__ nstart,
                            const __half* __restrict__ hs1, const float* __restrict__ dis,
                            const float* __restrict__ b1v, const float* __restrict__ W2,
                            float* __restrict__ hs2, int N) {
    __shared__ float w2s[HID * C_OUT];
    __shared__ float b1s[HID];
    int tid = threadIdx.x;
    if (tid < HID * C_OUT) w2s[tid] = W2[tid];
    if (tid < HID) b1s[tid] = b1v[tid];
    __syncthreads();
    int ldn = tid >> 1, q = tid & 1;
    int n = blockIdx.x * 128 + ldn;
    if (n >= N) return;
    uint e = nstart[n], en = nstart[n + 1];
    const uint4* hb = reinterpret_cast<const uint4*>(hs1) + q;  // row = idx*2 + q
    float a[8];
#pragma unroll
    for (int j = 0; j < 8; ++j) a[j] = 0.f;
    while (e + 8 <= en) {
        uint i0 = __builtin_nontemporal_load(rec + e);
        uint i1 = __builtin_nontemporal_load(rec + e + 1);
        uint i2 = __builtin_nontemporal_load(rec + e + 2);
        uint i3 = __builtin_nontemporal_load(rec + e + 3);
        uint i4 = __builtin_nontemporal_load(rec + e + 4);
        uint i5 = __builtin_nontemporal_load(rec + e + 5);
        uint i6 = __builtin_nontemporal_load(rec + e + 6);
        uint i7 = __builtin_nontemporal_load(rec + e + 7);
        uint4 v0 = hb[(size_t)i0 << 1];
        uint4 v1 = hb[(size_t)i1 << 1];
        uint4 v2 = hb[(size_t)i2 << 1];
        uint4 v3 = hb[(size_t)i3 << 1];
        uint4 v4 = hb[(size_t)i4 << 1];
        uint4 v5 = hb[(size_t)i5 << 1];
        uint4 v6 = hb[(size_t)i6 << 1];
        uint4 v7 = hb[(size_t)i7 << 1];
        acc8(v0, a); acc8(v1, a); acc8(v2, a); acc8(v3, a);
        acc8(v4, a); acc8(v5, a); acc8(v6, a); acc8(v7, a);
        e += 8;
    }
    while (e < en) {
        uint i0 = __builtin_nontemporal_load(rec + e);
        uint4 v = hb[(size_t)i0 << 1];
        acc8(v, a);
        ++e;
    }
    uint4 sv = hb[(size_t)n << 1];
    float s[8];
    {
        float2 f;
        f = __half22float2(*reinterpret_cast<const __half2*>(&sv.x)); s[0] = f.x; s[1] = f.y;
        f = __half22float2(*reinterpret_cast<const __half2*>(&sv.y)); s[2] = f.x; s[3] = f.y;
        f = __half22float2(*reinterpret_cast<const __half2*>(&sv.z)); s[4] = f.x; s[5] = f.y;
        f = __half22float2(*reinterpret_cast<const __half2*>(&sv.w)); s[6] = f.x; s[7] = f.y;
    }
    float dv = dis[n];
    float r[8];
#pragma unroll
    for (int j = 0; j < 8; ++j)
        r[j] = fmaxf(dv * (a[j] + s[j]) + b1s[q * 8 + j], 0.f);
    float p[C_OUT];
#pragma unroll
    for (int c = 0; c < C_OUT; ++c) {
        float t = 0.f;
#pragma unroll
        for (int j = 0; j < 8; ++j) t += r[j] * w2s[(q * 8 + j) * C_OUT + c];
        p[c] = t;
    }
#pragma unroll
    for (int c = 0; c < C_OUT; ++c) p[c] += __shfl_xor(p[c], 1);
    float4 o;
    o.x = p[q * 4 + 0] * dv;
    o.y = p[q * 4 + 1] * dv;
    o.z = p[q * 4 + 2] * dv;
    o.w = p[q * 4 + 3] * dv;
    *reinterpret_cast<float4*>(hs2 + ((size_t)n << 3) + (q << 2)) = o;
}

// ---- layer 2: 2 lanes/node, float4 gathers (3.2 MB fp32 table), 8-deep MLP; fused fin2 ----
__global__ void agg2_kernel(const uint* __restrict__ rec, const uint* __restrict__ nstart,
                            const float* __restrict__ hs2, const float* __restrict__ dis,
                            const float* __restrict__ b2v, float* __restrict__ out, int N) {
    int tid = threadIdx.x;
    int ldn = tid >> 1, q = tid & 1;
    int n = blockIdx.x * 128 + ldn;
    if (n >= N) return;
    uint e = nstart[n], en = nstart[n + 1];
    const float* hq = hs2 + (q << 2);
    float ax = 0.f, ay = 0.f, az = 0.f, aw = 0.f;
    while (e + 8 <= en) {
        uint i0 = __builtin_nontemporal_load(rec + e);
        uint i1 = __builtin_nontemporal_load(rec + e + 1);
        uint i2 = __builtin_nontemporal_load(rec + e + 2);
        uint i3 = __builtin_nontemporal_load(rec + e + 3);
        uint i4 = __builtin_nontemporal_load(rec + e + 4);
        uint i5 = __builtin_nontemporal_load(rec + e + 5);
        uint i6 = __builtin_nontemporal_load(rec + e + 6);
        uint i7 = __builtin_nontemporal_load(rec + e + 7);
        float4 v0 = *reinterpret_cast<const float4*>(hq + ((size_t)i0 << 3));
        float4 v1 = *reinterpret_cast<const float4*>(hq + ((size_t)i1 << 3));
        float4 v2 = *reinterpret_cast<const float4*>(hq + ((size_t)i2 << 3));
        float4 v3 = *reinterpret_cast<const float4*>(hq + ((size_t)i3 << 3));
        float4 v4 = *reinterpret_cast<const float4*>(hq + ((size_t)i4 << 3));
        float4 v5 = *reinterpret_cast<const float4*>(hq + ((size_t)i5 << 3));
        float4 v6 = *reinterpret_cast<const float4*>(hq + ((size_t)i6 << 3));
        float4 v7 = *reinterpret_cast<const float4*>(hq + ((size_t)i7 << 3));
        ax += ((v0.x + v1.x) + (v2.x + v3.x)) + ((v4.x + v5.x) + (v6.x + v7.x));
        ay += ((v0.y + v1.y) + (v2.y + v3.y)) + ((v4.y + v5.y) + (v6.y + v7.y));
        az += ((v0.z + v1.z) + (v2.z + v3.z)) + ((v4.z + v5.z) + (v6.z + v7.z));
        aw += ((v0.w + v1.w) + (v2.w + v3.w)) + ((v4.w + v5.w) + (v6.w + v7.w));
        e += 8;
    }
    while (e < en) {
        uint i0 = __builtin_nontemporal_load(rec + e);
        float4 v = *reinterpret_cast<const float4*>(hq + ((size_t)i0 << 3));
        ax += v.x; ay += v.y; az += v.z; aw += v.w;
        ++e;
    }
    float4 self = *reinterpret_cast<const float4*>(hq + ((size_t)n << 3));
    float dv = dis[n];
    float4 o;
    o.x = dv * (ax + self.x) + b2v[q * 4 + 0];
    o.y = dv * (ay + self.y) + b2v[q * 4 + 1];
    o.z = dv * (az + self.z) + b2v[q * 4 + 2];
    o.w = dv * (aw + self.w) + b2v[q * 4 + 3];
    *reinterpret_cast<float4*>(out + ((size_t)n << 3) + (q << 2)) = o;
}

extern "C" void kernel_launch(void* const* d_in, const int* in_sizes, int n_in,
                              void* d_out, int out_size, void* d_ws, size_t ws_size,
                              hipStream_t stream) {
    const float* x  = (const float*)d_in[0];
    const int*   ei = (const int*)d_in[1];
    const float* W1 = (const float*)d_in[2];
    const float* b1 = (const float*)d_in[3];
    const float* W2 = (const float*)d_in[4];
    const float* b2 = (const float*)d_in[5];
    float* out = (float*)d_out;

    int N = in_sizes[0] / F_IN;
    int E = in_sizes[1] / 2;
    const int* src = ei;
    const int* dst = ei + E;

    int NB = (N + BSZ - 1) / BSZ;                    // 1563
    int CE = (((E + G1 - 1) / G1) + 3) & ~3;         // per-chunk range, multiple of 4

    // workspace layout (4-byte units); 16B-sensitive arrays first
    float*  hs2   = (float*)d_ws;                    // 8N floats   (16B aligned)
    __half* hs1   = (__half*)(hs2 + (size_t)8 * N);  // 16N halves = 8N words (16B aligned)
    float*  dis   = (float*)(hs2 + (size_t)16 * N);  // N
    uint*   nstart = (uint*)(dis + N);               // N+1
    uint*   rec   = nstart + N + 1;                  // E
    uint*   counts = rec + E;                        // NB*G1
    uint*   btot  = counts + (size_t)NB * G1;        // NB
    uint*   bbase = btot + NB;                       // NB+1

    const int B = 256;
    count_kernel<<<G1, B, 0, stream>>>(dst, counts, E, CE, NB);
    scanA_kernel<<<NB, G1, 0, stream>>>(counts, btot);
    scanB_kernel<<<1, B, 0, stream>>>(btot, bbase, NB, E);
    place_kernel<<<G1, B, 0, stream>>>(src, dst, counts, bbase, rec, E, CE, NB);
    sortdis_kernel<<<NB, B, 0, stream>>>(rec, bbase, nstart, dis, N, NB);
    h1_kernel<<<(N + B - 1) / B, B, 0, stream>>>(x, W1, dis, hs1, N);
    agg1_kernel<<<(N + 127) / 128, B, 0, stream>>>(rec, nstart, hs1, dis, b1, W2, hs2, N);
    agg2_kernel<<<(N + 127) / 128, B, 0, stream>>>(rec, nstart, hs2, dis, b2, out, N);
}